// Round 9
// baseline (1736.849 us; speedup 1.0000x reference)
//
#include <hip/hip_runtime.h>
#include <hip/hip_bf16.h>
#include <cstddef>

// ---------------------------------------------------------------------------
// 3-layer GATv2, MI355X.
//   GEMMs: bf16x3 MFMA (hi+lo split = fp32-level accuracy).
//     layer 1  : gemm_mfma_k  (A fp32, split in-kernel)   [round-6 proven]
//     layers2/3: gemm_pre_k   (A pre-split bf16 hi/lo, reg-prefetch pipeline,
//                              __launch_bounds__(256,2) to prevent spill)
//   Inter-layer h stored as bf16 hi/lo pairs (same bytes as fp32).
//   Attention: CSR over dst + fused per-node online-softmax aggregation.
// ---------------------------------------------------------------------------

static inline int cdiv_h(int a, int b) { return (a + b - 1) / b; }

typedef __attribute__((ext_vector_type(8))) short short8v;
typedef __attribute__((ext_vector_type(4))) float float4v;

// ---------------- bf16 helpers ----------------
__device__ inline unsigned short f2bf_rne(float f) {
    unsigned u = __float_as_uint(f);
    return (unsigned short)((u + 0x7fffu + ((u >> 16) & 1u)) >> 16);
}
__device__ inline float bf2f(unsigned short h) {
    return __uint_as_float((unsigned)h << 16);
}

// ---------------- edge dtype detect + convert ----------------
__global__ void detect_k(const unsigned* __restrict__ w, int* __restrict__ flag, int nwords) {
    __shared__ int any;
    if (threadIdx.x == 0) any = 0;
    __syncthreads();
    int lim = nwords < 4096 ? nwords : 4096;
    for (int i = 1 + 2 * (int)threadIdx.x; i < lim; i += 512)
        if (w[i]) any = 1;               // benign race
    __syncthreads();
    if (threadIdx.x == 0) *flag = (any == 0) ? 1 : 0;   // 1 => int64 layout
}

__global__ void cvt_k(const void* __restrict__ ei, const int* __restrict__ flag,
                      int* __restrict__ s32, int* __restrict__ d32, int E, int N) {
    int e = blockIdx.x * blockDim.x + threadIdx.x;
    if (e >= E) return;
    int s, d;
    if (*flag) {
        const long long* p = (const long long*)ei;
        s = (int)p[e]; d = (int)p[E + e];
    } else {
        const int* p = (const int*)ei;
        s = p[e]; d = p[E + e];
    }
    s = s < 0 ? 0 : (s >= N ? N - 1 : s);
    d = d < 0 ? 0 : (d >= N ? N - 1 : d);
    s32[e] = s; d32[e] = d;
}

// ---------------- CSR build ----------------
__global__ void init_csr_k(int* __restrict__ counts, int* __restrict__ cursor, int n) {
    int i = blockIdx.x * blockDim.x + threadIdx.x;
    if (i < n) { counts[i] = 1; cursor[i] = 0; }   // 1 = self-loop
}

__global__ void count_k(const int* __restrict__ d32, int* __restrict__ counts, int E) {
    int e = blockIdx.x * blockDim.x + threadIdx.x;
    if (e < E) atomicAdd(&counts[d32[e]], 1);
}

__device__ inline int wave_incl_scan(int v) {
    #pragma unroll
    for (int d = 1; d < 64; d <<= 1) {
        int t = __shfl_up(v, d, 64);
        if (((int)threadIdx.x & 63) >= d) v += t;
    }
    return v;
}

__global__ void scan_k(const int* __restrict__ counts, int* __restrict__ offsets, int n) {
    __shared__ int wsums[16];
    __shared__ int carry_s;
    if (threadIdx.x == 0) carry_s = 0;
    __syncthreads();
    int lane = threadIdx.x & 63, wid = threadIdx.x >> 6;
    for (int base = 0; base < n; base += 1024) {
        int i = base + (int)threadIdx.x;
        int v = (i < n) ? counts[i] : 0;
        int incl = wave_incl_scan(v);
        if (lane == 63) wsums[wid] = incl;
        __syncthreads();
        if (wid == 0) {
            int s = (lane < 16) ? wsums[lane] : 0;
            #pragma unroll
            for (int d = 1; d < 16; d <<= 1) {
                int t = __shfl_up(s, d, 64);
                if (lane >= d) s += t;
            }
            if (lane < 16) wsums[lane] = s;
        }
        __syncthreads();
        int carry = carry_s;
        int waveoff = (wid == 0) ? 0 : wsums[wid - 1];
        int total = wsums[15];
        if (i < n) offsets[i + 1] = carry + waveoff + incl;
        __syncthreads();
        if (threadIdx.x == 0) carry_s = carry + total;
    }
    if (threadIdx.x == 0) offsets[0] = 0;
}

__global__ void fill_k(const int* __restrict__ s32, const int* __restrict__ d32,
                       const int* __restrict__ offs, int* __restrict__ cursor,
                       int* __restrict__ csr_src, int E, int ET) {
    int e = blockIdx.x * blockDim.x + threadIdx.x;
    if (e >= ET) return;
    int s, d;
    if (e < E) { s = s32[e]; d = d32[e]; }
    else       { s = d = e - E; }
    int p = offs[d] + atomicAdd(&cursor[d], 1);
    csr_src[p] = s;
}

// ---------------- masks ----------------
__global__ void masks_k(const float* __restrict__ x, float* __restrict__ m1,
                        float* __restrict__ m2, int n) {
    int i = blockIdx.x * blockDim.x + threadIdx.x;
    if (i < n) {
        float v = x[(size_t)i * 128];
        m1[i] = (v == 5.0f) ? 1.0f : 0.0f;
        m2[i] = (v == 1.0f) ? 1.0f : 0.0f;
    }
}

// ---------------- weight split: W[K][Nc] fp32 -> W^T hi/lo bf16 [Nc][K] ----------------
__global__ void split_wT_k(const float* __restrict__ W, unsigned short* __restrict__ hiT,
                           unsigned short* __restrict__ loT, int KN, int K, int ncShift) {
    int i = blockIdx.x * blockDim.x + threadIdx.x;
    if (i >= KN) return;
    int k = i >> ncShift;
    int c = i - (k << ncShift);
    float v = W[i];
    unsigned short h = f2bf_rne(v);
    float r = v - bf2f(h);
    unsigned short l = f2bf_rne(r);
    hiT[(size_t)c * K + k] = h;
    loT[(size_t)c * K + k] = l;
}

// ---------------- GEMM (layer 1): C = A[M,K](fp32) @ (Whi+Wlo)[K,Nc] ----------------
// round-6 proven version: in-kernel A split, no prefetch.
__global__ __launch_bounds__(256) void gemm_mfma_k(
        const float* __restrict__ A, const unsigned short* __restrict__ WThi,
        const unsigned short* __restrict__ WTlo, float* __restrict__ C,
        int M, int K, int Nc) {
    __shared__ __align__(16) unsigned short Ah[128][40];
    __shared__ __align__(16) unsigned short Al[128][40];
    __shared__ __align__(16) unsigned short Bh[128][40];
    __shared__ __align__(16) unsigned short Bl[128][40];

    const int tid = threadIdx.x;
    const int lane = tid & 63, wid = tid >> 6;
    const int kg = lane >> 4;
    const int wm = (wid >> 1) * 64, wn = (wid & 1) * 64;
    const int bm = blockIdx.y * 128, bn = blockIdx.x * 128;

    float4v acc[4][4];
    #pragma unroll
    for (int m = 0; m < 4; m++)
        #pragma unroll
        for (int n = 0; n < 4; n++) acc[m][n] = float4v{0.f, 0.f, 0.f, 0.f};

    const int arow_s = tid >> 3;
    const int acol4 = (tid & 7) * 4;
    const int bc_s = tid & 127;
    const int bk0_s = (tid >> 7) * 16;

    for (int k0 = 0; k0 < K; k0 += 32) {
        #pragma unroll
        for (int p = 0; p < 4; p++) {
            int row = arow_s + p * 32;
            int grow = bm + row;
            float4 av = make_float4(0.f, 0.f, 0.f, 0.f);
            if (grow < M) av = *(const float4*)(A + (size_t)grow * K + k0 + acol4);
            unsigned u0 = __float_as_uint(av.x), u1 = __float_as_uint(av.y);
            unsigned u2 = __float_as_uint(av.z), u3 = __float_as_uint(av.w);
            unsigned hi01 = (u0 >> 16) | (u1 & 0xffff0000u);
            unsigned hi23 = (u2 >> 16) | (u3 & 0xffff0000u);
            float r0 = av.x - __uint_as_float(u0 & 0xffff0000u);
            float r1 = av.y - __uint_as_float(u1 & 0xffff0000u);
            float r2 = av.z - __uint_as_float(u2 & 0xffff0000u);
            float r3 = av.w - __uint_as_float(u3 & 0xffff0000u);
            unsigned lo01 = (__float_as_uint(r0) >> 16) | (__float_as_uint(r1) & 0xffff0000u);
            unsigned lo23 = (__float_as_uint(r2) >> 16) | (__float_as_uint(r3) & 0xffff0000u);
            *(uint2*)&Ah[row][acol4] = make_uint2(hi01, hi23);
            *(uint2*)&Al[row][acol4] = make_uint2(lo01, lo23);
        }
        {
            const size_t gb = (size_t)(bn + bc_s) * K + k0 + bk0_s;
            uint4 h0 = *(const uint4*)(WThi + gb);
            uint4 h1 = *(const uint4*)(WThi + gb + 8);
            uint4 l0 = *(const uint4*)(WTlo + gb);
            uint4 l1 = *(const uint4*)(WTlo + gb + 8);
            *(uint4*)&Bh[bc_s][bk0_s]     = h0;
            *(uint4*)&Bh[bc_s][bk0_s + 8] = h1;
            *(uint4*)&Bl[bc_s][bk0_s]     = l0;
            *(uint4*)&Bl[bc_s][bk0_s + 8] = l1;
        }
        __syncthreads();

        short8v ah[4], al[4];
        #pragma unroll
        for (int m = 0; m < 4; m++) {
            int ar = wm + m * 16 + (lane & 15);
            ah[m] = *(const short8v*)&Ah[ar][kg * 8];
            al[m] = *(const short8v*)&Al[ar][kg * 8];
        }
        #pragma unroll
        for (int n = 0; n < 4; n++) {
            int bc = wn + n * 16 + (lane & 15);
            short8v bh = *(const short8v*)&Bh[bc][kg * 8];
            short8v bl = *(const short8v*)&Bl[bc][kg * 8];
            #pragma unroll
            for (int m = 0; m < 4; m++) {
                acc[m][n] = __builtin_amdgcn_mfma_f32_16x16x32_bf16(ah[m], bh, acc[m][n], 0, 0, 0);
                acc[m][n] = __builtin_amdgcn_mfma_f32_16x16x32_bf16(al[m], bh, acc[m][n], 0, 0, 0);
                acc[m][n] = __builtin_amdgcn_mfma_f32_16x16x32_bf16(ah[m], bl, acc[m][n], 0, 0, 0);
            }
        }
        __syncthreads();
    }

    #pragma unroll
    for (int m = 0; m < 4; m++) {
        int row0 = bm + wm + m * 16 + kg * 4;
        #pragma unroll
        for (int n = 0; n < 4; n++) {
            int col = bn + wn + n * 16 + (lane & 15);
            #pragma unroll
            for (int r = 0; r < 4; r++) {
                int gr = row0 + r;
                if (gr < M) C[(size_t)gr * Nc + col] = acc[m][n][r];
            }
        }
    }
}

// ---------------- GEMM (layers 2/3): A pre-split bf16 hi/lo, reg-prefetch ----
// C[M,Nc] = (Ahi+Alo)[M,K] @ (Whi+Wlo)[K,Nc], 3 MFMA products.
// Staging is pure 16B copies; next K-tile prefetched in regs under MFMA.
// __launch_bounds__(256,2): budget 8 waves/CU at <=256 VGPR -> no spill.
__global__ __launch_bounds__(256, 2) void gemm_pre_k(
        const unsigned short* __restrict__ Ahi, const unsigned short* __restrict__ Alo,
        const unsigned short* __restrict__ WThi, const unsigned short* __restrict__ WTlo,
        float* __restrict__ C, int M, int K, int Nc) {
    __shared__ __align__(16) unsigned short Ah[128][40];
    __shared__ __align__(16) unsigned short Al[128][40];
    __shared__ __align__(16) unsigned short Bh[128][40];
    __shared__ __align__(16) unsigned short Bl[128][40];

    const int tid = threadIdx.x;
    const int lane = tid & 63, wid = tid >> 6;
    const int kg = lane >> 4;
    const int wm = (wid >> 1) * 64, wn = (wid & 1) * 64;
    const int bm = blockIdx.y * 128, bn = blockIdx.x * 128;

    float4v acc[4][4];
    #pragma unroll
    for (int m = 0; m < 4; m++)
        #pragma unroll
        for (int n = 0; n < 4; n++) acc[m][n] = float4v{0.f, 0.f, 0.f, 0.f};

    const int r_s  = tid & 127;           // A row / B col
    const int h_s  = (tid >> 7) * 16;     // 16-short half within 32-short k-tile
    const bool aok = (bm + r_s) < M;

    const unsigned short* pAh = Ahi + (size_t)(bm + r_s) * K + h_s;
    const unsigned short* pAl = Alo + (size_t)(bm + r_s) * K + h_s;
    const unsigned short* pBh = WThi + (size_t)(bn + r_s) * K + h_s;
    const unsigned short* pBl = WTlo + (size_t)(bn + r_s) * K + h_s;

    uint4 aH[2], aL[2], bH[2], bL[2];
    const uint4 z4 = make_uint4(0u, 0u, 0u, 0u);

    // prologue: k-tile 0 -> regs
    aH[0] = aok ? *(const uint4*)pAh : z4;  aH[1] = aok ? *(const uint4*)(pAh + 8) : z4;
    aL[0] = aok ? *(const uint4*)pAl : z4;  aL[1] = aok ? *(const uint4*)(pAl + 8) : z4;
    bH[0] = *(const uint4*)pBh;             bH[1] = *(const uint4*)(pBh + 8);
    bL[0] = *(const uint4*)pBl;             bL[1] = *(const uint4*)(pBl + 8);
    pAh += 32; pAl += 32; pBh += 32; pBl += 32;

    for (int k0 = 0; k0 < K; k0 += 32) {
        // regs -> LDS
        *(uint4*)&Ah[r_s][h_s]     = aH[0];  *(uint4*)&Ah[r_s][h_s + 8] = aH[1];
        *(uint4*)&Al[r_s][h_s]     = aL[0];  *(uint4*)&Al[r_s][h_s + 8] = aL[1];
        *(uint4*)&Bh[r_s][h_s]     = bH[0];  *(uint4*)&Bh[r_s][h_s + 8] = bH[1];
        *(uint4*)&Bl[r_s][h_s]     = bL[0];  *(uint4*)&Bl[r_s][h_s + 8] = bL[1];
        __syncthreads();

        // issue next k-tile loads; latency hides under MFMA below
        if (k0 + 32 < K) {
            aH[0] = aok ? *(const uint4*)pAh : z4;  aH[1] = aok ? *(const uint4*)(pAh + 8) : z4;
            aL[0] = aok ? *(const uint4*)pAl : z4;  aL[1] = aok ? *(const uint4*)(pAl + 8) : z4;
            bH[0] = *(const uint4*)pBh;             bH[1] = *(const uint4*)(pBh + 8);
            bL[0] = *(const uint4*)pBl;             bL[1] = *(const uint4*)(pBl + 8);
            pAh += 32; pAl += 32; pBh += 32; pBl += 32;
        }

        short8v ah[4], al[4];
        #pragma unroll
        for (int m = 0; m < 4; m++) {
            int ar = wm + m * 16 + (lane & 15);
            ah[m] = *(const short8v*)&Ah[ar][kg * 8];
            al[m] = *(const short8v*)&Al[ar][kg * 8];
        }
        #pragma unroll
        for (int n = 0; n < 4; n++) {
            int bc = wn + n * 16 + (lane & 15);
            short8v bh = *(const short8v*)&Bh[bc][kg * 8];
            short8v bl = *(const short8v*)&Bl[bc][kg * 8];
            #pragma unroll
            for (int m = 0; m < 4; m++) {
                acc[m][n] = __builtin_amdgcn_mfma_f32_16x16x32_bf16(ah[m], bh, acc[m][n], 0, 0, 0);
                acc[m][n] = __builtin_amdgcn_mfma_f32_16x16x32_bf16(al[m], bh, acc[m][n], 0, 0, 0);
                acc[m][n] = __builtin_amdgcn_mfma_f32_16x16x32_bf16(ah[m], bl, acc[m][n], 0, 0, 0);
            }
        }
        __syncthreads();
    }

    #pragma unroll
    for (int m = 0; m < 4; m++) {
        int row0 = bm + wm + m * 16 + kg * 4;
        #pragma unroll
        for (int n = 0; n < 4; n++) {
            int col = bn + wn + n * 16 + (lane & 15);
            #pragma unroll
            for (int r = 0; r < 4; r++) {
                int gr = row0 + r;
                if (gr < M) C[(size_t)gr * Nc + col] = acc[m][n][r];
            }
        }
    }
}

// ---------------- fused per-node: logits + online softmax + aggregate ----------------
// !LAST: output split to bf16 hi/lo (consumed by gemm_pre_k). LAST: fp32 out.
template <int H, int C, bool LAST>
__global__ __launch_bounds__(256) void fused_k(
        const float* __restrict__ xl, const float* __restrict__ xrc,
        const float* __restrict__ att, const float* __restrict__ bias,
        const int* __restrict__ offs, const int* __restrict__ csr_src,
        float* __restrict__ outp, unsigned short* __restrict__ outH,
        unsigned short* __restrict__ outL, int n0, int n1) {
    constexpr int FO = H * C;          // 256 / 128
    constexpr int PER = FO / 64;       // 4 / 2
    constexpr int LPH = C / PER;       // lanes per head: 16 / 64
    int node = n0 + blockIdx.x * (256 / 64) + ((int)threadIdx.x >> 6);
    if (node >= n1) return;
    int lane = threadIdx.x & 63;

    float xr_[PER], att_[PER];
    {
        const float* xp = xrc + (size_t)(node - n0) * FO + lane * PER;
        #pragma unroll
        for (int k = 0; k < PER; k++) { xr_[k] = xp[k]; att_[k] = att[lane * PER + k]; }
    }
    float m = -1e30f, s = 0.f;
    float acc[PER] = {};
    int jb = offs[node], je = offs[node + 1];
    for (int j = jb; j < je; j++) {
        int src = csr_src[j];
        float xv[PER];
        const float* xp = xl + (size_t)src * FO + lane * PER;
        if constexpr (PER == 4) {
            float4 t = *(const float4*)xp;
            xv[0] = t.x; xv[1] = t.y; xv[2] = t.z; xv[3] = t.w;
        } else {
            float2 t = *(const float2*)xp;
            xv[0] = t.x; xv[1] = t.y;
        }
        float p = 0.f;
        #pragma unroll
        for (int k = 0; k < PER; k++) {
            float v = xv[k] + xr_[k];
            v = (v > 0.f) ? v : 0.2f * v;      // GATv2 negative_slope
            p += v * att_[k];
        }
        #pragma unroll
        for (int off = LPH / 2; off > 0; off >>= 1) p += __shfl_xor(p, off, 64);
        float mn = fmaxf(m, p);
        float scale = __expf(m - mn);
        float w = __expf(p - mn);
        s = s * scale + w;
        #pragma unroll
        for (int k = 0; k < PER; k++) acc[k] = acc[k] * scale + w * xv[k];
        m = mn;
    }
    float inv = 1.0f / s;
    if constexpr (LAST) {
        #pragma unroll
        for (int k = 0; k < PER; k++)
            outp[(size_t)node * FO + lane * PER + k] = acc[k] * inv + bias[lane * PER + k];
    } else {
        unsigned short hs[PER], ls[PER];
        #pragma unroll
        for (int k = 0; k < PER; k++) {
            float v = acc[k] * inv + bias[lane * PER + k];
            v = (v > 0.f) ? v : 0.01f * v;     // inter-layer LeakyReLU
            unsigned short h = f2bf_rne(v);
            hs[k] = h;
            ls[k] = f2bf_rne(v - bf2f(h));
        }
        // PER==4 here (layers 1,2)
        *(ushort4*)(outH + (size_t)node * FO + lane * PER) =
            make_ushort4(hs[0], hs[1], hs[2], hs[3]);
        *(ushort4*)(outL + (size_t)node * FO + lane * PER) =
            make_ushort4(ls[0], ls[1], ls[2], ls[3]);
    }
}

// ---------------------------------------------------------------------------
extern "C" void kernel_launch(void* const* d_in, const int* in_sizes, int n_in,
                              void* d_out, int out_size, void* d_ws, size_t ws_size,
                              hipStream_t stream) {
    const float* x    = (const float*)d_in[0];
    const void*  ei   = d_in[1];
    const float* Wl1  = (const float*)d_in[2];
    const float* Wr1  = (const float*)d_in[3];
    const float* att1 = (const float*)d_in[4];
    const float* b1   = (const float*)d_in[5];
    const float* Wl2  = (const float*)d_in[6];
    const float* Wr2  = (const float*)d_in[7];
    const float* att2 = (const float*)d_in[8];
    const float* b2   = (const float*)d_in[9];
    const float* Wl3  = (const float*)d_in[10];
    const float* Wr3  = (const float*)d_in[11];
    const float* att3 = (const float*)d_in[12];
    const float* b3   = (const float*)d_in[13];

    const int N  = in_sizes[0] / 128;     // 100000
    const int E  = in_sizes[1] / 2;       // 800000
    const int ET = E + N;

    // ---- workspace: ints | WT bf16 splits | B1h/B1l | B2 | XRC ----
    char* base   = (char*)d_ws;
    int* flag    = (int*)base;
    int* src32   = flag + 1;
    int* dst32   = src32 + E;
    int* counts  = dst32 + E;
    int* cursor  = counts + N;
    int* offs    = cursor + N;            // N+1
    int* csr_src = offs + (N + 1);        // ET
    size_t off16 = (((size_t)((char*)(csr_src + ET) - base)) + 15) & ~(size_t)15;
    unsigned short* wt = (unsigned short*)(base + off16);
    unsigned short* w1l_h = wt;            wt += 128 * 256;
    unsigned short* w1l_l = wt;            wt += 128 * 256;
    unsigned short* w1r_h = wt;            wt += 128 * 256;
    unsigned short* w1r_l = wt;            wt += 128 * 256;
    unsigned short* w2l_h = wt;            wt += 256 * 256;
    unsigned short* w2l_l = wt;            wt += 256 * 256;
    unsigned short* w2r_h = wt;            wt += 256 * 256;
    unsigned short* w2r_l = wt;            wt += 256 * 256;
    unsigned short* w3l_h = wt;            wt += 256 * 128;
    unsigned short* w3l_l = wt;            wt += 256 * 128;
    unsigned short* w3r_h = wt;            wt += 256 * 128;
    unsigned short* w3r_l = wt;            wt += 256 * 128;
    unsigned short* B1h = wt;              // h hi, N*256 bf16
    unsigned short* B1l = B1h + (size_t)N * 256;   // h lo
    float* B2  = (float*)(B1l + (size_t)N * 256);  // xl buffer, N*256 fp32
    float* XRC = B2 + (size_t)N * 256;    // xr chunk
    size_t used = (size_t)((char*)XRC - base);
    long long availf = ((long long)ws_size - (long long)used) / 4;
    int CH = (int)(availf / 256);
    if (CH > N) CH = N;
    if (CH < 2048) CH = 2048;
    const int nch = cdiv_h(N, CH);

    float* outF  = (float*)d_out;              // [N,128]
    float* maskE = outF + (size_t)N * 128;
    float* maskA = maskE + N;

    // ---- edge convert + CSR build ----
    detect_k<<<1, 256, 0, stream>>>((const unsigned*)ei, flag, in_sizes[1]);
    cvt_k<<<cdiv_h(E, 256), 256, 0, stream>>>(ei, flag, src32, dst32, E, N);
    init_csr_k<<<cdiv_h(N, 256), 256, 0, stream>>>(counts, cursor, N);
    count_k<<<cdiv_h(E, 256), 256, 0, stream>>>(dst32, counts, E);
    scan_k<<<1, 1024, 0, stream>>>(counts, offs, N);
    fill_k<<<cdiv_h(ET, 256), 256, 0, stream>>>(src32, dst32, offs, cursor, csr_src, E, ET);

    masks_k<<<cdiv_h(N, 256), 256, 0, stream>>>(x, maskE, maskA, N);

    // ---- weight splits (hi/lo bf16, transposed) ----
    split_wT_k<<<cdiv_h(128 * 256, 256), 256, 0, stream>>>(Wl1, w1l_h, w1l_l, 128 * 256, 128, 8);
    split_wT_k<<<cdiv_h(128 * 256, 256), 256, 0, stream>>>(Wr1, w1r_h, w1r_l, 128 * 256, 128, 8);
    split_wT_k<<<cdiv_h(256 * 256, 256), 256, 0, stream>>>(Wl2, w2l_h, w2l_l, 256 * 256, 256, 8);
    split_wT_k<<<cdiv_h(256 * 256, 256), 256, 0, stream>>>(Wr2, w2r_h, w2r_l, 256 * 256, 256, 8);
    split_wT_k<<<cdiv_h(256 * 128, 256), 256, 0, stream>>>(Wl3, w3l_h, w3l_l, 256 * 128, 256, 7);
    split_wT_k<<<cdiv_h(256 * 128, 256), 256, 0, stream>>>(Wr3, w3r_h, w3r_l, 256 * 128, 256, 7);

    const int gy = cdiv_h(N, 128);

    // ---- layer 1: Fin=128, H=4, C=64 (A = x fp32, round-6 kernel) ----
    gemm_mfma_k<<<dim3(2, gy), 256, 0, stream>>>(x, w1l_h, w1l_l, B2, N, 128, 256);
    for (int c = 0; c < nch; c++) {
        int n0 = c * CH, n1 = (n0 + CH < N) ? n0 + CH : N, M = n1 - n0;
        gemm_mfma_k<<<dim3(2, cdiv_h(M, 128)), 256, 0, stream>>>(x + (size_t)n0 * 128, w1r_h, w1r_l, XRC, M, 128, 256);
        fused_k<4, 64, false><<<cdiv_h(M, 4), 256, 0, stream>>>(B2, XRC, att1, b1, offs, csr_src, nullptr, B1h, B1l, n0, n1);
    }

    // ---- layer 2: Fin=256, H=4, C=64 (A = B1 hi/lo, prefetch kernel) ----
    gemm_pre_k<<<dim3(2, gy), 256, 0, stream>>>(B1h, B1l, w2l_h, w2l_l, B2, N, 256, 256);
    for (int c = 0; c < nch; c++) {
        int n0 = c * CH, n1 = (n0 + CH < N) ? n0 + CH : N, M = n1 - n0;
        gemm_pre_k<<<dim3(2, cdiv_h(M, 128)), 256, 0, stream>>>(B1h + (size_t)n0 * 256, B1l + (size_t)n0 * 256, w2r_h, w2r_l, XRC, M, 256, 256);
        fused_k<4, 64, false><<<cdiv_h(M, 4), 256, 0, stream>>>(B2, XRC, att2, b2, offs, csr_src, nullptr, B1h, B1l, n0, n1);
    }

    // ---- layer 3: Fin=256, H=1, C=128 -> d_out ----
    // In-place B1h/B1l overwrite by layer-2 fused is safe: the full-N Wl-GEMM
    // reads all rows before the chunk loop; each chunk's Wr-GEMM reads rows
    // [n0,n1) before that chunk's fused writes them; later chunks' rows are
    // untouched by earlier fused writes (same argument as fp32 B1, rounds 2-6).
    gemm_pre_k<<<dim3(1, gy), 256, 0, stream>>>(B1h, B1l, w3l_h, w3l_l, B2, N, 256, 128);
    for (int c = 0; c < nch; c++) {
        int n0 = c * CH, n1 = (n0 + CH < N) ? n0 + CH : N, M = n1 - n0;
        gemm_pre_k<<<dim3(1, cdiv_h(M, 128)), 256, 0, stream>>>(B1h + (size_t)n0 * 256, B1l + (size_t)n0 * 256, w3r_h, w3r_l, XRC, M, 256, 128);
        fused_k<1, 128, true><<<cdiv_h(M, 4), 256, 0, stream>>>(B2, XRC, att3, b3, offs, csr_src, outF, nullptr, nullptr, n0, n1);
    }
}

// Round 14
// 1212.537 us; speedup vs baseline: 1.4324x; 1.4324x over previous
//
#include <hip/hip_runtime.h>
#include <hip/hip_bf16.h>
#include <cstddef>

// ---------------------------------------------------------------------------
// 3-layer GATv2, MI355X.
//   GEMMs: one kernel, bf16x3 MFMA (hi+lo split = fp32-level accuracy).
//     A and W both pre-split to bf16 hi/lo; staging via global_load_lds
//     (HBM->LDS direct, no VGPR round-trip -> no spill), double-buffered
//     T3-minimum schedule: STAGE(next) -> compute(cur) -> barrier -> swap.
//     LDS linear + both-sides XOR swizzle (slot ^= (row>>1)&3) for 2-way banks.
//   Inter-layer h stored as bf16 hi/lo pairs; x pre-split into upper halves
//   of the h buffers (overlap-safe, see comments).
//   Attention: CSR over dst + fused per-node online-softmax aggregation.
// ---------------------------------------------------------------------------

static inline int cdiv_h(int a, int b) { return (a + b - 1) / b; }

typedef __attribute__((ext_vector_type(8))) short short8v;
typedef __attribute__((ext_vector_type(4))) float float4v;

// ---------------- bf16 helpers ----------------
__device__ inline unsigned short f2bf_rne(float f) {
    unsigned u = __float_as_uint(f);
    return (unsigned short)((u + 0x7fffu + ((u >> 16) & 1u)) >> 16);
}
__device__ inline float bf2f(unsigned short h) {
    return __uint_as_float((unsigned)h << 16);
}

// async 16B global -> LDS (wave-uniform LDS base + lane*16; global addr per-lane)
__device__ __forceinline__ void gl_lds16(const void* g, void* l) {
    __builtin_amdgcn_global_load_lds(
        (const __attribute__((address_space(1))) void*)g,
        (__attribute__((address_space(3))) void*)l, 16, 0, 0);
}

// ---------------- edge dtype detect + convert ----------------
__global__ void detect_k(const unsigned* __restrict__ w, int* __restrict__ flag, int nwords) {
    __shared__ int any;
    if (threadIdx.x == 0) any = 0;
    __syncthreads();
    int lim = nwords < 4096 ? nwords : 4096;
    for (int i = 1 + 2 * (int)threadIdx.x; i < lim; i += 512)
        if (w[i]) any = 1;               // benign race
    __syncthreads();
    if (threadIdx.x == 0) *flag = (any == 0) ? 1 : 0;   // 1 => int64 layout
}

__global__ void cvt_k(const void* __restrict__ ei, const int* __restrict__ flag,
                      int* __restrict__ s32, int* __restrict__ d32, int E, int N) {
    int e = blockIdx.x * blockDim.x + threadIdx.x;
    if (e >= E) return;
    int s, d;
    if (*flag) {
        const long long* p = (const long long*)ei;
        s = (int)p[e]; d = (int)p[E + e];
    } else {
        const int* p = (const int*)ei;
        s = p[e]; d = p[E + e];
    }
    s = s < 0 ? 0 : (s >= N ? N - 1 : s);
    d = d < 0 ? 0 : (d >= N ? N - 1 : d);
    s32[e] = s; d32[e] = d;
}

// ---------------- CSR build ----------------
__global__ void init_csr_k(int* __restrict__ counts, int* __restrict__ cursor, int n) {
    int i = blockIdx.x * blockDim.x + threadIdx.x;
    if (i < n) { counts[i] = 1; cursor[i] = 0; }   // 1 = self-loop
}

__global__ void count_k(const int* __restrict__ d32, int* __restrict__ counts, int E) {
    int e = blockIdx.x * blockDim.x + threadIdx.x;
    if (e < E) atomicAdd(&counts[d32[e]], 1);
}

__device__ inline int wave_incl_scan(int v) {
    #pragma unroll
    for (int d = 1; d < 64; d <<= 1) {
        int t = __shfl_up(v, d, 64);
        if (((int)threadIdx.x & 63) >= d) v += t;
    }
    return v;
}

__global__ void scan_k(const int* __restrict__ counts, int* __restrict__ offsets, int n) {
    __shared__ int wsums[16];
    __shared__ int carry_s;
    if (threadIdx.x == 0) carry_s = 0;
    __syncthreads();
    int lane = threadIdx.x & 63, wid = threadIdx.x >> 6;
    for (int base = 0; base < n; base += 1024) {
        int i = base + (int)threadIdx.x;
        int v = (i < n) ? counts[i] : 0;
        int incl = wave_incl_scan(v);
        if (lane == 63) wsums[wid] = incl;
        __syncthreads();
        if (wid == 0) {
            int s = (lane < 16) ? wsums[lane] : 0;
            #pragma unroll
            for (int d = 1; d < 16; d <<= 1) {
                int t = __shfl_up(s, d, 64);
                if (lane >= d) s += t;
            }
            if (lane < 16) wsums[lane] = s;
        }
        __syncthreads();
        int carry = carry_s;
        int waveoff = (wid == 0) ? 0 : wsums[wid - 1];
        int total = wsums[15];
        if (i < n) offsets[i + 1] = carry + waveoff + incl;
        __syncthreads();
        if (threadIdx.x == 0) carry_s = carry + total;
    }
    if (threadIdx.x == 0) offsets[0] = 0;
}

__global__ void fill_k(const int* __restrict__ s32, const int* __restrict__ d32,
                       const int* __restrict__ offs, int* __restrict__ cursor,
                       int* __restrict__ csr_src, int E, int ET) {
    int e = blockIdx.x * blockDim.x + threadIdx.x;
    if (e >= ET) return;
    int s, d;
    if (e < E) { s = s32[e]; d = d32[e]; }
    else       { s = d = e - E; }
    int p = offs[d] + atomicAdd(&cursor[d], 1);
    csr_src[p] = s;
}

// ---------------- masks ----------------
__global__ void masks_k(const float* __restrict__ x, float* __restrict__ m1,
                        float* __restrict__ m2, int n) {
    int i = blockIdx.x * blockDim.x + threadIdx.x;
    if (i < n) {
        float v = x[(size_t)i * 128];
        m1[i] = (v == 5.0f) ? 1.0f : 0.0f;
        m2[i] = (v == 1.0f) ? 1.0f : 0.0f;
    }
}

// ---------------- weight split: W[K][Nc] fp32 -> W^T hi/lo bf16 [Nc][K] ----------------
__global__ void split_wT_k(const float* __restrict__ W, unsigned short* __restrict__ hiT,
                           unsigned short* __restrict__ loT, int KN, int K, int ncShift) {
    int i = blockIdx.x * blockDim.x + threadIdx.x;
    if (i >= KN) return;
    int k = i >> ncShift;
    int c = i - (k << ncShift);
    float v = W[i];
    unsigned short h = f2bf_rne(v);
    float r = v - bf2f(h);
    unsigned short l = f2bf_rne(r);
    hiT[(size_t)c * K + k] = h;
    loT[(size_t)c * K + k] = l;
}

// ---------------- x split: [n] fp32 -> hi/lo bf16, same layout ----------------
__global__ void split_x_k(const float* __restrict__ x, unsigned short* __restrict__ xh,
                          unsigned short* __restrict__ xl_, int n4) {
    int i = blockIdx.x * blockDim.x + threadIdx.x;
    if (i >= n4) return;
    float4 v = *(const float4*)(x + (size_t)i * 4);
    unsigned short h0 = f2bf_rne(v.x), h1 = f2bf_rne(v.y), h2 = f2bf_rne(v.z), h3 = f2bf_rne(v.w);
    *(ushort4*)(xh + (size_t)i * 4) = make_ushort4(h0, h1, h2, h3);
    *(ushort4*)(xl_ + (size_t)i * 4) = make_ushort4(
        f2bf_rne(v.x - bf2f(h0)), f2bf_rne(v.y - bf2f(h1)),
        f2bf_rne(v.z - bf2f(h2)), f2bf_rne(v.w - bf2f(h3)));
}

// ---------------- MFMA GEMM: C[M,Nc] = (Ahi+Alo)[M,K] @ (Whi+Wlo)[K,Nc] ------
// 128x128 tile, 256 thr = 4 waves (2x2), wave tile 64x64, 3 MFMA per frag pair.
// Staging: global_load_lds 16B direct to LDS, double-buffered (T3-minimum):
//   STAGE(buf^1, t+1) ; compute(buf) ; __syncthreads (drains vmcnt) ; swap.
// LDS tiles linear [128 rows][32 shorts]; 16B slot swizzle: slot ^= (row>>1)&3
// applied to BOTH the global source column and the ds_read address (rule #21).
__global__ __launch_bounds__(256) void gemm_glds_k(
        const unsigned short* __restrict__ Ahi, const unsigned short* __restrict__ Alo,
        const unsigned short* __restrict__ WThi, const unsigned short* __restrict__ WTlo,
        float* __restrict__ C, int M, int K, int Nc) {
    __shared__ __align__(16) unsigned short L[2][4][128 * 32];   // 64 KB: Ah,Al,Bh,Bl x dbuf

    const int tid = threadIdx.x;
    const int lane = tid & 63, wid = tid >> 6;
    const int kg = lane >> 4;
    const int wm = (wid >> 1) * 64, wn = (wid & 1) * 64;
    const int bm = blockIdx.y * 128, bn = blockIdx.x * 128;

    // ---- staging map: wave covers rows [wid*32, wid*32+32) in 2 segs of 16 ----
    const int r0 = wid * 32;
    const int rl = lane >> 2;          // row within segment
    const int sl = lane & 3;           // 16B slot within row's 64B
    const unsigned short* gp[8];
    #pragma unroll
    for (int s = 0; s < 2; s++) {
        int r = r0 + s * 16 + rl;
        int cq = sl ^ ((r >> 1) & 3);  // pre-swizzled global 16B column
        int ga = bm + r; if (ga >= M) ga = M - 1;   // clamp: dup row, never stored
        int gb = bn + r;               // Nc multiple of 128 -> always in range
        gp[0 * 2 + s] = Ahi  + (size_t)ga * K + cq * 8;
        gp[1 * 2 + s] = Alo  + (size_t)ga * K + cq * 8;
        gp[2 * 2 + s] = WThi + (size_t)gb * K + cq * 8;
        gp[3 * 2 + s] = WTlo + (size_t)gb * K + cq * 8;
    }
    const int lb0 = r0 * 32, lb1 = (r0 + 16) * 32;   // wave-uniform LDS bases (shorts)

    // ---- loop-invariant ds_read offsets (same swizzle) ----
    int offA[4], offB[4];
    #pragma unroll
    for (int m = 0; m < 4; m++) {
        int ar = wm + m * 16 + (lane & 15);
        offA[m] = ar * 32 + (kg ^ ((ar >> 1) & 3)) * 8;
        int br = wn + m * 16 + (lane & 15);
        offB[m] = br * 32 + (kg ^ ((br >> 1) & 3)) * 8;
    }

    float4v acc[4][4];
    #pragma unroll
    for (int m = 0; m < 4; m++)
        #pragma unroll
        for (int n = 0; n < 4; n++) acc[m][n] = float4v{0.f, 0.f, 0.f, 0.f};

    auto STAGE = [&](int buf) {
        #pragma unroll
        for (int mat = 0; mat < 4; mat++) {
            gl_lds16(gp[mat * 2 + 0], &L[buf][mat][lb0]);
            gl_lds16(gp[mat * 2 + 1], &L[buf][mat][lb1]);
        }
        #pragma unroll
        for (int i = 0; i < 8; i++) gp[i] += 32;
    };

    const int nt = K >> 5;
    int cur = 0;
    STAGE(0);
    __syncthreads();                      // vmcnt(0) drain: tile 0 resident

    for (int t = 0; t < nt; t++) {
        if (t + 1 < nt) STAGE(cur ^ 1);   // async into other buffer, no wait

        const unsigned short* Ah = &L[cur][0][0];
        const unsigned short* Al = &L[cur][1][0];
        const unsigned short* Bh = &L[cur][2][0];
        const unsigned short* Bl = &L[cur][3][0];
        short8v ah[4], al[4];
        #pragma unroll
        for (int m = 0; m < 4; m++) {
            ah[m] = *(const short8v*)(Ah + offA[m]);
            al[m] = *(const short8v*)(Al + offA[m]);
        }
        #pragma unroll
        for (int n = 0; n < 4; n++) {
            short8v bh = *(const short8v*)(Bh + offB[n]);
            short8v bl = *(const short8v*)(Bl + offB[n]);
            #pragma unroll
            for (int m = 0; m < 4; m++) {
                acc[m][n] = __builtin_amdgcn_mfma_f32_16x16x32_bf16(ah[m], bh, acc[m][n], 0, 0, 0);
                acc[m][n] = __builtin_amdgcn_mfma_f32_16x16x32_bf16(al[m], bh, acc[m][n], 0, 0, 0);
                acc[m][n] = __builtin_amdgcn_mfma_f32_16x16x32_bf16(ah[m], bl, acc[m][n], 0, 0, 0);
            }
        }
        __syncthreads();                  // drains vmcnt: next tile resident
        cur ^= 1;
    }

    // ---- epilogue: C/D layout col=lane&15, row=kg*4+r (m89-verified) ----
    #pragma unroll
    for (int m = 0; m < 4; m++) {
        int row0 = bm + wm + m * 16 + kg * 4;
        #pragma unroll
        for (int n = 0; n < 4; n++) {
            int col = bn + wn + n * 16 + (lane & 15);
            #pragma unroll
            for (int r = 0; r < 4; r++) {
                int gr = row0 + r;
                if (gr < M) C[(size_t)gr * Nc + col] = acc[m][n][r];
            }
        }
    }
}

// ---------------- fused per-node: logits + online softmax + aggregate ----------------
// !LAST: output split to bf16 hi/lo (consumed by gemm_glds_k). LAST: fp32 out.
template <int H, int C, bool LAST>
__global__ __launch_bounds__(256) void fused_k(
        const float* __restrict__ xl, const float* __restrict__ xrc,
        const float* __restrict__ att, const float* __restrict__ bias,
        const int* __restrict__ offs, const int* __restrict__ csr_src,
        float* __restrict__ outp, unsigned short* __restrict__ outH,
        unsigned short* __restrict__ outL, int n0, int n1) {
    constexpr int FO = H * C;          // 256 / 128
    constexpr int PER = FO / 64;       // 4 / 2
    constexpr int LPH = C / PER;       // lanes per head: 16 / 64
    int node = n0 + blockIdx.x * (256 / 64) + ((int)threadIdx.x >> 6);
    if (node >= n1) return;
    int lane = threadIdx.x & 63;

    float xr_[PER], att_[PER];
    {
        const float* xp = xrc + (size_t)(node - n0) * FO + lane * PER;
        #pragma unroll
        for (int k = 0; k < PER; k++) { xr_[k] = xp[k]; att_[k] = att[lane * PER + k]; }
    }
    float m = -1e30f, s = 0.f;
    float acc[PER] = {};
    int jb = offs[node], je = offs[node + 1];
    for (int j = jb; j < je; j++) {
        int src = csr_src[j];
        float xv[PER];
        const float* xp = xl + (size_t)src * FO + lane * PER;
        if constexpr (PER == 4) {
            float4 t = *(const float4*)xp;
            xv[0] = t.x; xv[1] = t.y; xv[2] = t.z; xv[3] = t.w;
        } else {
            float2 t = *(const float2*)xp;
            xv[0] = t.x; xv[1] = t.y;
        }
        float p = 0.f;
        #pragma unroll
        for (int k = 0; k < PER; k++) {
            float v = xv[k] + xr_[k];
            v = (v > 0.f) ? v : 0.2f * v;      // GATv2 negative_slope
            p += v * att_[k];
        }
        #pragma unroll
        for (int off = LPH / 2; off > 0; off >>= 1) p += __shfl_xor(p, off, 64);
        float mn = fmaxf(m, p);
        float scale = __expf(m - mn);
        float w = __expf(p - mn);
        s = s * scale + w;
        #pragma unroll
        for (int k = 0; k < PER; k++) acc[k] = acc[k] * scale + w * xv[k];
        m = mn;
    }
    float inv = 1.0f / s;
    if constexpr (LAST) {
        #pragma unroll
        for (int k = 0; k < PER; k++)
            outp[(size_t)node * FO + lane * PER + k] = acc[k] * inv + bias[lane * PER + k];
    } else {
        unsigned short hs[PER], ls[PER];
        #pragma unroll
        for (int k = 0; k < PER; k++) {
            float v = acc[k] * inv + bias[lane * PER + k];
            v = (v > 0.f) ? v : 0.01f * v;     // inter-layer LeakyReLU
            unsigned short h = f2bf_rne(v);
            hs[k] = h;
            ls[k] = f2bf_rne(v - bf2f(h));
        }
        // PER==4 here (layers 1,2)
        *(ushort4*)(outH + (size_t)node * FO + lane * PER) =
            make_ushort4(hs[0], hs[1], hs[2], hs[3]);
        *(ushort4*)(outL + (size_t)node * FO + lane * PER) =
            make_ushort4(ls[0], ls[1], ls[2], ls[3]);
    }
}

// ---------------------------------------------------------------------------
extern "C" void kernel_launch(void* const* d_in, const int* in_sizes, int n_in,
                              void* d_out, int out_size, void* d_ws, size_t ws_size,
                              hipStream_t stream) {
    const float* x    = (const float*)d_in[0];
    const void*  ei   = d_in[1];
    const float* Wl1  = (const float*)d_in[2];
    const float* Wr1  = (const float*)d_in[3];
    const float* att1 = (const float*)d_in[4];
    const float* b1   = (const float*)d_in[5];
    const float* Wl2  = (const float*)d_in[6];
    const float* Wr2  = (const float*)d_in[7];
    const float* att2 = (const float*)d_in[8];
    const float* b2   = (const float*)d_in[9];
    const float* Wl3  = (const float*)d_in[10];
    const float* Wr3  = (const float*)d_in[11];
    const float* att3 = (const float*)d_in[12];
    const float* b3   = (const float*)d_in[13];

    const int N  = in_sizes[0] / 128;     // 100000
    const int E  = in_sizes[1] / 2;       // 800000
    const int ET = E + N;

    // ---- workspace: ints | WT bf16 splits | B1h/B1l | B2 | XRC ----
    char* base   = (char*)d_ws;
    int* flag    = (int*)base;
    int* src32   = flag + 1;
    int* dst32   = src32 + E;
    int* counts  = dst32 + E;
    int* cursor  = counts + N;
    int* offs    = cursor + N;            // N+1
    int* csr_src = offs + (N + 1);        // ET
    size_t off16 = (((size_t)((char*)(csr_src + ET) - base)) + 15) & ~(size_t)15;
    unsigned short* wt = (unsigned short*)(base + off16);
    unsigned short* w1l_h = wt;            wt += 128 * 256;
    unsigned short* w1l_l = wt;            wt += 128 * 256;
    unsigned short* w1r_h = wt;            wt += 128 * 256;
    unsigned short* w1r_l = wt;            wt += 128 * 256;
    unsigned short* w2l_h = wt;            wt += 256 * 256;
    unsigned short* w2l_l = wt;            wt += 256 * 256;
    unsigned short* w2r_h = wt;            wt += 256 * 256;
    unsigned short* w2r_l = wt;            wt += 256 * 256;
    unsigned short* w3l_h = wt;            wt += 256 * 128;
    unsigned short* w3l_l = wt;            wt += 256 * 128;
    unsigned short* w3r_h = wt;            wt += 256 * 128;
    unsigned short* w3r_l = wt;            wt += 256 * 128;
    unsigned short* B1h = wt;              // h hi, N*256 bf16
    unsigned short* B1l = B1h + (size_t)N * 256;   // h lo
    float* B2  = (float*)(B1l + (size_t)N * 256);  // xl buffer, N*256 fp32
    float* XRC = B2 + (size_t)N * 256;    // xr chunk
    size_t used = (size_t)((char*)XRC - base);
    long long availf = ((long long)ws_size - (long long)used) / 4;
    int CH = (int)(availf / 256);
    if (CH > N) CH = N;
    if (CH < 2048) CH = 2048;
    const int nch = cdiv_h(N, CH);

    // x pre-split lives in the UPPER halves of B1h/B1l ([N,128] each).
    // Safety: layer-1 fused chunk c writes h offsets [n0*256, n1*256); x-split
    // row r sits at N*128 + r*128. Rows r >= n1 (still needed) start at
    // N*128 + n1*128 >= n1*256 for all n1 <= N -> never clobbered before use.
    unsigned short* Xh = B1h + (size_t)N * 128;
    unsigned short* Xl = B1l + (size_t)N * 128;

    float* outF  = (float*)d_out;              // [N,128]
    float* maskE = outF + (size_t)N * 128;
    float* maskA = maskE + N;

    // ---- edge convert + CSR build ----
    detect_k<<<1, 256, 0, stream>>>((const unsigned*)ei, flag, in_sizes[1]);
    cvt_k<<<cdiv_h(E, 256), 256, 0, stream>>>(ei, flag, src32, dst32, E, N);
    init_csr_k<<<cdiv_h(N, 256), 256, 0, stream>>>(counts, cursor, N);
    count_k<<<cdiv_h(E, 256), 256, 0, stream>>>(dst32, counts, E);
    scan_k<<<1, 1024, 0, stream>>>(counts, offs, N);
    fill_k<<<cdiv_h(ET, 256), 256, 0, stream>>>(src32, dst32, offs, cursor, csr_src, E, ET);

    masks_k<<<cdiv_h(N, 256), 256, 0, stream>>>(x, maskE, maskA, N);

    // ---- splits: weights (hi/lo, transposed) + x (hi/lo, same layout) ----
    split_wT_k<<<cdiv_h(128 * 256, 256), 256, 0, stream>>>(Wl1, w1l_h, w1l_l, 128 * 256, 128, 8);
    split_wT_k<<<cdiv_h(128 * 256, 256), 256, 0, stream>>>(Wr1, w1r_h, w1r_l, 128 * 256, 128, 8);
    split_wT_k<<<cdiv_h(256 * 256, 256), 256, 0, stream>>>(Wl2, w2l_h, w2l_l, 256 * 256, 256, 8);
    split_wT_k<<<cdiv_h(256 * 256, 256), 256, 0, stream>>>(Wr2, w2r_h, w2r_l, 256 * 256, 256, 8);
    split_wT_k<<<cdiv_h(256 * 128, 256), 256, 0, stream>>>(Wl3, w3l_h, w3l_l, 256 * 128, 256, 7);
    split_wT_k<<<cdiv_h(256 * 128, 256), 256, 0, stream>>>(Wr3, w3r_h, w3r_l, 256 * 128, 256, 7);
    split_x_k<<<cdiv_h(N * 32, 256), 256, 0, stream>>>(x, Xh, Xl, N * 32);

    const int gy = cdiv_h(N, 128);

    // ---- layer 1: Fin=128, H=4, C=64 ----
    gemm_glds_k<<<dim3(2, gy), 256, 0, stream>>>(Xh, Xl, w1l_h, w1l_l, B2, N, 128, 256);
    for (int c = 0; c < nch; c++) {
        int n0 = c * CH, n1 = (n0 + CH < N) ? n0 + CH : N, M = n1 - n0;
        gemm_glds_k<<<dim3(2, cdiv_h(M, 128)), 256, 0, stream>>>(
            Xh + (size_t)n0 * 128, Xl + (size_t)n0 * 128, w1r_h, w1r_l, XRC, M, 128, 256);
        fused_k<4, 64, false><<<cdiv_h(M, 4), 256, 0, stream>>>(B2, XRC, att1, b1, offs, csr_src, nullptr, B1h, B1l, n0, n1);
    }

    // ---- layer 2: Fin=256, H=4, C=64 (in-place h overwrite per chunk, proven) ----
    gemm_glds_k<<<dim3(2, gy), 256, 0, stream>>>(B1h, B1l, w2l_h, w2l_l, B2, N, 256, 256);
    for (int c = 0; c < nch; c++) {
        int n0 = c * CH, n1 = (n0 + CH < N) ? n0 + CH : N, M = n1 - n0;
        gemm_glds_k<<<dim3(2, cdiv_h(M, 128)), 256, 0, stream>>>(
            B1h + (size_t)n0 * 256, B1l + (size_t)n0 * 256, w2r_h, w2r_l, XRC, M, 256, 256);
        fused_k<4, 64, false><<<cdiv_h(M, 4), 256, 0, stream>>>(B2, XRC, att2, b2, offs, csr_src, nullptr, B1h, B1l, n0, n1);
    }

    // ---- layer 3: Fin=256, H=1, C=128 -> d_out ----
    gemm_glds_k<<<dim3(1, gy), 256, 0, stream>>>(B1h, B1l, w3l_h, w3l_l, B2, N, 256, 128);
    for (int c = 0; c < nch; c++) {
        int n0 = c * CH, n1 = (n0 + CH < N) ? n0 + CH : N, M = n1 - n0;
        gemm_glds_k<<<dim3(1, cdiv_h(M, 128)), 256, 0, stream>>>(
            B1h + (size_t)n0 * 256, B1l + (size_t)n0 * 256, w3r_h, w3r_l, XRC, M, 256, 128);
        fused_k<1, 128, true><<<cdiv_h(M, 4), 256, 0, stream>>>(B2, XRC, att3, b3, offs, csr_src, outF, nullptr, nullptr, n0, n1);
    }
}